// Round 6
// baseline (280.022 us; speedup 1.0000x reference)
//
#include <hip/hip_runtime.h>
#include <hip/hip_bf16.h>

#define S_LEN 2048
#define HDIM  1024
#define NHEADS 16
#define HD    64
#define QKV_STRIDE (S_LEN * 2 * HDIM)   // 4194304 elements per tensor

typedef __attribute__((ext_vector_type(8))) short short8;
typedef __attribute__((ext_vector_type(4))) float float4v;

// cheap bf16 convert: round-half-up (bias ~2^-24 rel, negligible vs bf16 eps)
__device__ __forceinline__ unsigned short f2bf(float f) {
  return (unsigned short)((__builtin_bit_cast(unsigned int, f) + 0x8000u) >> 16);
}
// pack two floats -> two bf16 in one u32 via v_perm_b32 (3 VALU ops)
__device__ __forceinline__ unsigned int pkbf(float a, float b) {
  unsigned int ua = __builtin_bit_cast(unsigned int, a) + 0x8000u;
  unsigned int ub = __builtin_bit_cast(unsigned int, b) + 0x8000u;
  return __builtin_amdgcn_perm(ub, ua, 0x07060302u);  // {ub.hi16, ua.hi16}
}

__device__ __forceinline__ void async_copy16(const void* g, void* l) {
  __builtin_amdgcn_global_load_lds((__attribute__((address_space(1))) const void*)g,
                                   (__attribute__((address_space(3))) void*)l, 16, 0, 0);
}

// ---------------- cast X (fp32 -> bf16), 4 elems/thread ----------------
__global__ void cast_x_kernel(const float* __restrict__ X, unsigned short* __restrict__ Xb) {
  int i = blockIdx.x * blockDim.x + threadIdx.x;   // 0 .. 1048575
  float4 v = ((const float4*)X)[i];
  uint2 o;
  o.x = pkbf(v.x, v.y);
  o.y = pkbf(v.z, v.w);
  ((uint2*)Xb)[i] = o;
}

// ------------- transpose + cast weights: Wt[n][k] = bf16(W[k][n]) -------------
__global__ void trans_w_kernel(const float* __restrict__ W0, const float* __restrict__ W1,
                               const float* __restrict__ W2, const float* __restrict__ W3,
                               unsigned short* __restrict__ Wt) {
  __shared__ unsigned short tile[64][72];   // [n_loc][k_loc], padded
  const float* W = (blockIdx.z == 0) ? W0 : (blockIdx.z == 1) ? W1 : (blockIdx.z == 2) ? W2 : W3;
  unsigned short* out = Wt + (size_t)blockIdx.z * HDIM * HDIM;
  int n0 = blockIdx.x * 64, k0 = blockIdx.y * 64;
  int t = threadIdx.x;
#pragma unroll
  for (int it = 0; it < 4; ++it) {
    int idx = it * 256 + t;          // 1024 float4 chunks
    int r  = idx >> 4;               // k_loc 0..63
    int c4 = (idx & 15) * 4;         // n_loc
    float4 v = *(const float4*)&W[(size_t)(k0 + r) * HDIM + n0 + c4];
    tile[c4 + 0][r] = f2bf(v.x);
    tile[c4 + 1][r] = f2bf(v.y);
    tile[c4 + 2][r] = f2bf(v.z);
    tile[c4 + 3][r] = f2bf(v.w);
  }
  __syncthreads();
#pragma unroll
  for (int it = 0; it < 4; ++it) {
    int idx = it * 256 + t;
    int r  = idx >> 4;               // n_loc
    int c4 = (idx & 15) * 4;         // k_loc
    ushort4 o;
    o.x = tile[r][c4 + 0]; o.y = tile[r][c4 + 1];
    o.z = tile[r][c4 + 2]; o.w = tile[r][c4 + 3];
    *(ushort4*)&out[(size_t)(n0 + r) * HDIM + k0 + c4] = o;
  }
}

// ---------------- 128x128 bf16 MFMA GEMM, A(MxK) row-major, Bt(NxK) row-major ----------------
// mode 0: fp32 dense out[m*1024+n].
// mode 1: bf16; z==1 (K) -> (b,h,s,d) natural scatter;
//               z==0 (Q, pre-scaled by 0.125*log2e) and z==2 (V) -> (b,h,d,s) packed.
__global__ __launch_bounds__(256, 3) void gemm128_kernel(
    const unsigned short* __restrict__ A,
    const unsigned short* __restrict__ B0, const unsigned short* __restrict__ B1,
    const unsigned short* __restrict__ B2,
    void* __restrict__ outp, int mode)
{
  __shared__ unsigned short sA[128 * 32];
  __shared__ unsigned short sB[128 * 32];
  const int z = blockIdx.z;
  const unsigned short* Bt = (z == 0) ? B0 : (z == 1) ? B1 : B2;
  const int m0 = blockIdx.x * 128;
  const int n0 = blockIdx.y * 128;
  const int t = threadIdx.x;
  const int lane = t & 63;
  const int w = t >> 6;
  const int wm = w & 1, wn = w >> 1;

  const int sr  = lane >> 2;                  // row within 16
  const int scp = lane & 3;                   // physical chunk
  const int scl = scp ^ ((sr >> 1) & 3);      // logical (global) k-chunk
  const long ga0 = (long)(m0 + 16 * w + sr) * HDIM + scl * 8;
  const long ga1 = ga0 + 64l * HDIM;
  const long gb0 = (long)(n0 + 16 * w + sr) * HDIM + scl * 8;
  const long gb1 = gb0 + 64l * HDIM;
  unsigned short* lA0 = &sA[(16 * w) * 32];
  unsigned short* lA1 = &sA[(64 + 16 * w) * 32];
  unsigned short* lB0 = &sB[(16 * w) * 32];
  unsigned short* lB1 = &sB[(64 + 16 * w) * 32];

  const int fr = lane & 15;
  const int fq = lane >> 4;
  int offA[4], offB[4];
#pragma unroll
  for (int i = 0; i < 4; ++i) {
    int ra = wm * 64 + i * 16 + fr;
    offA[i] = ra * 32 + (fq ^ ((ra >> 1) & 3)) * 8;
    int rb = wn * 64 + i * 16 + fr;
    offB[i] = rb * 32 + (fq ^ ((rb >> 1) & 3)) * 8;
  }

  float4v acc[4][4] = {};

  for (int kk = 0; kk < HDIM; kk += 32) {
    __syncthreads();
    async_copy16(A + ga0 + kk, lA0);
    async_copy16(A + ga1 + kk, lA1);
    async_copy16(Bt + gb0 + kk, lB0);
    async_copy16(Bt + gb1 + kk, lB1);
    __syncthreads();
    short8 af[4], bf[4];
#pragma unroll
    for (int i = 0; i < 4; ++i) af[i] = *(const short8*)&sA[offA[i]];
#pragma unroll
    for (int i = 0; i < 4; ++i) bf[i] = *(const short8*)&sB[offB[i]];
#pragma unroll
    for (int mi = 0; mi < 4; ++mi)
#pragma unroll
      for (int ni = 0; ni < 4; ++ni)
        acc[mi][ni] = __builtin_amdgcn_mfma_f32_16x16x32_bf16(af[mi], bf[ni], acc[mi][ni], 0, 0, 0);
  }

  if (mode == 0) {
    float* out = (float*)outp;
#pragma unroll
    for (int mi = 0; mi < 4; ++mi)
#pragma unroll
      for (int ni = 0; ni < 4; ++ni)
#pragma unroll
        for (int rg = 0; rg < 4; ++rg) {
          int m = m0 + wm * 64 + mi * 16 + fq * 4 + rg;
          int n = n0 + wn * 64 + ni * 16 + fr;
          out[(size_t)m * HDIM + n] = acc[mi][ni][rg];
        }
  } else if (z != 1) {
    // transposed (b, h, d, s): 4 consecutive s per lane -> packed 8B stores.
    // z==0 (Q): fold softmax scale 0.125*log2(e) in here.
    const float scl = (z == 0) ? 0.18033688011112042f : 1.0f;
    unsigned short* out = (unsigned short*)outp + (size_t)z * QKV_STRIDE;
#pragma unroll
    for (int mi = 0; mi < 4; ++mi)
#pragma unroll
      for (int ni = 0; ni < 4; ++ni) {
        int m = m0 + wm * 64 + mi * 16 + fq * 4;   // s base (multiple of 4)
        int n = n0 + wn * 64 + ni * 16 + fr;
        int b = m >> 11, s = m & 2047, hh = n >> 6, d = n & 63;
        uint2 pk;
        pk.x = pkbf(acc[mi][ni][0] * scl, acc[mi][ni][1] * scl);
        pk.y = pkbf(acc[mi][ni][2] * scl, acc[mi][ni][3] * scl);
        *(uint2*)&out[(((size_t)(b * NHEADS + hh)) * HD + d) * S_LEN + s] = pk;
      }
  } else {
    unsigned short* out = (unsigned short*)outp + (size_t)z * QKV_STRIDE;
#pragma unroll
    for (int mi = 0; mi < 4; ++mi)
#pragma unroll
      for (int ni = 0; ni < 4; ++ni)
#pragma unroll
        for (int rg = 0; rg < 4; ++rg) {
          int m = m0 + wm * 64 + mi * 16 + fq * 4 + rg;
          int n = n0 + wn * 64 + ni * 16 + fr;
          int b = m >> 11, s = m & 2047, hh = n >> 6, d = n & 63;
          out[(((size_t)(b * NHEADS + hh)) * S_LEN + s) * HD + d] = f2bf(acc[mi][ni][rg]);
        }
  }
}

// ---------------- flash attention: S^T form, fixed-base softmax, V direct from L1 ----------------
// K is LDS-staged (shared 8x across waves). V fragments are 16B-contiguous in the
// (b,h,d,s) layout and are loaded straight from global per-lane (L1-resident tile),
// moving ~half the operand traffic off the LDS pipe onto the near-idle vmem pipe.
// V loads are depth-1 software-pipelined across the PV ks-loop.
__global__ __launch_bounds__(512, 4) void attn_kernel(
    const unsigned short* __restrict__ Qtp,
    const unsigned short* __restrict__ Kp,
    const unsigned short* __restrict__ Vtp,
    const int* __restrict__ mask,
    unsigned short* __restrict__ ctx)
{
  __shared__ unsigned short sK[128 * 64];      // [k][d], 16B chunks xor by k&7
  __shared__ unsigned short sP[8][16 * 128];   // per-wave P^T strip [q][k], 8B chunks xor fr&14

  const int bh = blockIdx.y;
  const int b = bh >> 4;
  const int h = bh & 15;
  const size_t base = (size_t)bh * (S_LEN * HD);
  const int q0 = blockIdx.x * 128;
  const int t = threadIdx.x;
  const int lane = t & 63;
  const int w = t >> 6;                        // 0..7
  const int fr = lane & 15;
  const int fq = lane >> 4;
  unsigned short* sPw = sP[w];

  // Q fragments from transposed layout, once per block (16 scalar loads)
  short8 qfr[2];
#pragma unroll
  for (int ks = 0; ks < 2; ++ks)
#pragma unroll
    for (int j = 0; j < 8; ++j)
      qfr[ks][j] = (short)Qtp[base + (size_t)(ks * 32 + fq * 8 + j) * S_LEN + (q0 + w * 16 + fr)];

  // per-lane V base pointers: V^T row d = df*16+fr, chunk start fq*8
  const unsigned short* vbase[4];
#pragma unroll
  for (int df = 0; df < 4; ++df)
    vbase[df] = Vtp + base + (size_t)(df * 16 + fr) * S_LEN + fq * 8;

  float l_lane = 0.f;                          // per-lane partial sum of p
  float4v o_acc[4] = {};

  const int kr = lane >> 3, kc = lane & 7;     // K staging
  const float NEG = -1e30f;

  for (int kv0 = 0; kv0 < S_LEN; kv0 += 128) {
    __syncthreads();
    // stage K tile: wave w covers rows [w*16, w*16+16)
#pragma unroll
    for (int o = 0; o < 2; ++o) {
      int row0 = w * 16 + o * 8;
      async_copy16(Kp + base + (size_t)(kv0 + row0 + kr) * HD + ((kc ^ kr) * 8), &sK[row0 * HD]);
    }
    __syncthreads();

    // kick off V prefetch for ks=0 (in flight through QK^T + softmax)
    short8 vf[2][4];
#pragma unroll
    for (int df = 0; df < 4; ++df)
      vf[0][df] = *(const short8*)&vbase[df][kv0];

    // S^T = K · Q^T  (scores already in log2 domain: Q pre-scaled)
    float4v s_acc[8];
    const float4v zero4 = {0.f, 0.f, 0.f, 0.f};
#pragma unroll
    for (int kf = 0; kf < 8; ++kf) {
      int rk = kf * 16 + fr;
      short8 k0 = *(const short8*)&sK[rk * HD + ((fq ^ (fr & 7)) * 8)];
      short8 k1 = *(const short8*)&sK[rk * HD + (((4 + fq) ^ (fr & 7)) * 8)];
      float4v s = __builtin_amdgcn_mfma_f32_16x16x32_bf16(k0, qfr[0], zero4, 0, 0, 0);
      s_acc[kf] = __builtin_amdgcn_mfma_f32_16x16x32_bf16(k1, qfr[1], s, 0, 0, 0);
    }

    // mask -> exp2 -> pack P^T -> accumulate per-lane l. No cross-lane ops here.
    const int prow = fr * 128;
#pragma unroll
    for (int kf = 0; kf < 8; ++kf) {
      int4 mv = *(const int4*)&mask[b * S_LEN + kv0 + kf * 16 + fq * 4];
      float p0 = __builtin_amdgcn_exp2f(mv.x ? s_acc[kf][0] : NEG);
      float p1 = __builtin_amdgcn_exp2f(mv.y ? s_acc[kf][1] : NEG);
      float p2 = __builtin_amdgcn_exp2f(mv.z ? s_acc[kf][2] : NEG);
      float p3 = __builtin_amdgcn_exp2f(mv.w ? s_acc[kf][3] : NEG);
      l_lane += (p0 + p1) + (p2 + p3);
      uint2 pk;
      pk.x = pkbf(p0, p1);
      pk.y = pkbf(p2, p3);
      *(uint2*)&sPw[prow + (((kf * 4 + fq) ^ (fr & 14)) << 2)] = pk;
    }
    // no barrier: sP strip is per-wave; LDS ops are in-order within a wave

    // O^T += V^T · P^T  (V depth-1 prefetch: load ks+1 while computing ks)
#pragma unroll
    for (int ks = 0; ks < 4; ++ks) {
      if (ks < 3) {
#pragma unroll
        for (int df = 0; df < 4; ++df)
          vf[(ks + 1) & 1][df] = *(const short8*)&vbase[df][kv0 + (ks + 1) * 32];
      }
      short8 pf = *(const short8*)&sPw[prow + (((ks * 8 + fq * 2) ^ (fr & 14)) << 2)];
#pragma unroll
      for (int df = 0; df < 4; ++df)
        o_acc[df] = __builtin_amdgcn_mfma_f32_16x16x32_bf16(vf[ks & 1][df], pf, o_acc[df], 0, 0, 0);
    }
  }

  // final l reduction (only cross-lane ops in the whole kernel)
  float l = l_lane;
  l += __shfl_xor(l, 16);
  l += __shfl_xor(l, 32);
  float inv_l = 1.0f / l;

  // epilogue: O^T C-layout -> 4 consecutive d per lane -> packed 8B stores
  size_t rowoff = ((size_t)(b * S_LEN + q0 + w * 16 + fr)) * HDIM + h * HD;
#pragma unroll
  for (int df = 0; df < 4; ++df) {
    uint2 pk;
    pk.x = pkbf(o_acc[df][0] * inv_l, o_acc[df][1] * inv_l);
    pk.y = pkbf(o_acc[df][2] * inv_l, o_acc[df][3] * inv_l);
    *(uint2*)&ctx[rowoff + df * 16 + fq * 4] = pk;
  }
}

extern "C" void kernel_launch(void* const* d_in, const int* in_sizes, int n_in,
                              void* d_out, int out_size, void* d_ws, size_t ws_size,
                              hipStream_t stream) {
  const float* X  = (const float*)d_in[0];
  const int* mask = (const int*)d_in[1];
  const float* Wq = (const float*)d_in[2];
  const float* Wk = (const float*)d_in[3];
  const float* Wv = (const float*)d_in[4];
  const float* Wo = (const float*)d_in[5];
  float* out = (float*)d_out;

  char* ws = (char*)d_ws;
  // layout (40 MB): [0,8M) Xb then reused as CTX; [8M,16M) Wt x4; [16M,40M) Q^T,K,V^T bf16
  unsigned short* Xb  = (unsigned short*)(ws);
  unsigned short* Wt  = (unsigned short*)(ws + (8u << 20));
  unsigned short* QKV = (unsigned short*)(ws + (16u << 20));
  unsigned short* CTX = (unsigned short*)(ws);   // reuse Xb region (dead after QKV GEMM)

  cast_x_kernel<<<4096, 256, 0, stream>>>(X, Xb);
  trans_w_kernel<<<dim3(16, 16, 4), 256, 0, stream>>>(Wq, Wk, Wv, Wo, Wt);
  gemm128_kernel<<<dim3(32, 8, 3), 256, 0, stream>>>(
      Xb, Wt, Wt + (1u << 20), Wt + (2u << 20), QKV, 1);
  attn_kernel<<<dim3(16, 32), 512, 0, stream>>>(
      QKV, QKV + QKV_STRIDE, QKV + 2 * (size_t)QKV_STRIDE, mask, CTX);
  gemm128_kernel<<<dim3(32, 8, 1), 256, 0, stream>>>(
      CTX, Wt + (3u << 20), Wt + (3u << 20), Wt + (3u << 20), out, 0);
}

// Round 8
// 197.672 us; speedup vs baseline: 1.4166x; 1.4166x over previous
//
#include <hip/hip_runtime.h>
#include <hip/hip_bf16.h>

#define S_LEN 2048
#define HDIM  1024
#define NHEADS 16
#define HD    64
#define QKV_STRIDE (S_LEN * 2 * HDIM)   // 4194304 elements per tensor

typedef __attribute__((ext_vector_type(8))) short short8;
typedef __attribute__((ext_vector_type(4))) float float4v;

// cheap bf16 convert: round-half-up (bias ~2^-24 rel, negligible vs bf16 eps)
__device__ __forceinline__ unsigned short f2bf(float f) {
  return (unsigned short)((__builtin_bit_cast(unsigned int, f) + 0x8000u) >> 16);
}
// pack two floats -> two bf16 in one u32 via v_perm_b32 (3 VALU ops)
__device__ __forceinline__ unsigned int pkbf(float a, float b) {
  unsigned int ua = __builtin_bit_cast(unsigned int, a) + 0x8000u;
  unsigned int ub = __builtin_bit_cast(unsigned int, b) + 0x8000u;
  return __builtin_amdgcn_perm(ub, ua, 0x07060302u);  // {ub.hi16, ua.hi16}
}

__device__ __forceinline__ void async_copy16(const void* g, void* l) {
  __builtin_amdgcn_global_load_lds((__attribute__((address_space(1))) const void*)g,
                                   (__attribute__((address_space(3))) void*)l, 16, 0, 0);
}

// ---------------- cast X (fp32 -> bf16), 4 elems/thread ----------------
__global__ void cast_x_kernel(const float* __restrict__ X, unsigned short* __restrict__ Xb) {
  int i = blockIdx.x * blockDim.x + threadIdx.x;   // 0 .. 1048575
  float4 v = ((const float4*)X)[i];
  uint2 o;
  o.x = pkbf(v.x, v.y);
  o.y = pkbf(v.z, v.w);
  ((uint2*)Xb)[i] = o;
}

// ------------- transpose + cast weights: Wt[n][k] = bf16(W[k][n]) -------------
__global__ void trans_w_kernel(const float* __restrict__ W0, const float* __restrict__ W1,
                               const float* __restrict__ W2, const float* __restrict__ W3,
                               unsigned short* __restrict__ Wt) {
  __shared__ unsigned short tile[64][72];   // [n_loc][k_loc], padded
  const float* W = (blockIdx.z == 0) ? W0 : (blockIdx.z == 1) ? W1 : (blockIdx.z == 2) ? W2 : W3;
  unsigned short* out = Wt + (size_t)blockIdx.z * HDIM * HDIM;
  int n0 = blockIdx.x * 64, k0 = blockIdx.y * 64;
  int t = threadIdx.x;
#pragma unroll
  for (int it = 0; it < 4; ++it) {
    int idx = it * 256 + t;          // 1024 float4 chunks
    int r  = idx >> 4;               // k_loc 0..63
    int c4 = (idx & 15) * 4;         // n_loc
    float4 v = *(const float4*)&W[(size_t)(k0 + r) * HDIM + n0 + c4];
    tile[c4 + 0][r] = f2bf(v.x);
    tile[c4 + 1][r] = f2bf(v.y);
    tile[c4 + 2][r] = f2bf(v.z);
    tile[c4 + 3][r] = f2bf(v.w);
  }
  __syncthreads();
#pragma unroll
  for (int it = 0; it < 4; ++it) {
    int idx = it * 256 + t;
    int r  = idx >> 4;               // n_loc
    int c4 = (idx & 15) * 4;         // k_loc
    ushort4 o;
    o.x = tile[r][c4 + 0]; o.y = tile[r][c4 + 1];
    o.z = tile[r][c4 + 2]; o.w = tile[r][c4 + 3];
    *(ushort4*)&out[(size_t)(n0 + r) * HDIM + k0 + c4] = o;
  }
}

// ---------------- 128x128 bf16 MFMA GEMM, A(MxK) row-major, Bt(NxK) row-major ----------------
// mode 0: fp32 dense out[m*1024+n].
// mode 1: bf16; z==1 (K) -> (b,h,s,d) natural scatter;
//               z==0 (Q, pre-scaled by 0.125*log2e) and z==2 (V) -> (b,h,d,s) packed.
__global__ __launch_bounds__(256, 3) void gemm128_kernel(
    const unsigned short* __restrict__ A,
    const unsigned short* __restrict__ B0, const unsigned short* __restrict__ B1,
    const unsigned short* __restrict__ B2,
    void* __restrict__ outp, int mode)
{
  __shared__ unsigned short sA[128 * 32];
  __shared__ unsigned short sB[128 * 32];
  const int z = blockIdx.z;
  const unsigned short* Bt = (z == 0) ? B0 : (z == 1) ? B1 : B2;
  const int m0 = blockIdx.x * 128;
  const int n0 = blockIdx.y * 128;
  const int t = threadIdx.x;
  const int lane = t & 63;
  const int w = t >> 6;
  const int wm = w & 1, wn = w >> 1;

  const int sr  = lane >> 2;                  // row within 16
  const int scp = lane & 3;                   // physical chunk
  const int scl = scp ^ ((sr >> 1) & 3);      // logical (global) k-chunk
  const long ga0 = (long)(m0 + 16 * w + sr) * HDIM + scl * 8;
  const long ga1 = ga0 + 64l * HDIM;
  const long gb0 = (long)(n0 + 16 * w + sr) * HDIM + scl * 8;
  const long gb1 = gb0 + 64l * HDIM;
  unsigned short* lA0 = &sA[(16 * w) * 32];
  unsigned short* lA1 = &sA[(64 + 16 * w) * 32];
  unsigned short* lB0 = &sB[(16 * w) * 32];
  unsigned short* lB1 = &sB[(64 + 16 * w) * 32];

  const int fr = lane & 15;
  const int fq = lane >> 4;
  int offA[4], offB[4];
#pragma unroll
  for (int i = 0; i < 4; ++i) {
    int ra = wm * 64 + i * 16 + fr;
    offA[i] = ra * 32 + (fq ^ ((ra >> 1) & 3)) * 8;
    int rb = wn * 64 + i * 16 + fr;
    offB[i] = rb * 32 + (fq ^ ((rb >> 1) & 3)) * 8;
  }

  float4v acc[4][4] = {};

  for (int kk = 0; kk < HDIM; kk += 32) {
    __syncthreads();
    async_copy16(A + ga0 + kk, lA0);
    async_copy16(A + ga1 + kk, lA1);
    async_copy16(Bt + gb0 + kk, lB0);
    async_copy16(Bt + gb1 + kk, lB1);
    __syncthreads();
    short8 af[4], bf[4];
#pragma unroll
    for (int i = 0; i < 4; ++i) af[i] = *(const short8*)&sA[offA[i]];
#pragma unroll
    for (int i = 0; i < 4; ++i) bf[i] = *(const short8*)&sB[offB[i]];
#pragma unroll
    for (int mi = 0; mi < 4; ++mi)
#pragma unroll
      for (int ni = 0; ni < 4; ++ni)
        acc[mi][ni] = __builtin_amdgcn_mfma_f32_16x16x32_bf16(af[mi], bf[ni], acc[mi][ni], 0, 0, 0);
  }

  if (mode == 0) {
    float* out = (float*)outp;
#pragma unroll
    for (int mi = 0; mi < 4; ++mi)
#pragma unroll
      for (int ni = 0; ni < 4; ++ni)
#pragma unroll
        for (int rg = 0; rg < 4; ++rg) {
          int m = m0 + wm * 64 + mi * 16 + fq * 4 + rg;
          int n = n0 + wn * 64 + ni * 16 + fr;
          out[(size_t)m * HDIM + n] = acc[mi][ni][rg];
        }
  } else if (z != 1) {
    // transposed (b, h, d, s): 4 consecutive s per lane -> packed 8B stores.
    // z==0 (Q): fold softmax scale 0.125*log2(e) in here.
    const float scl = (z == 0) ? 0.18033688011112042f : 1.0f;
    unsigned short* out = (unsigned short*)outp + (size_t)z * QKV_STRIDE;
#pragma unroll
    for (int mi = 0; mi < 4; ++mi)
#pragma unroll
      for (int ni = 0; ni < 4; ++ni) {
        int m = m0 + wm * 64 + mi * 16 + fq * 4;   // s base (multiple of 4)
        int n = n0 + wn * 64 + ni * 16 + fr;
        int b = m >> 11, s = m & 2047, hh = n >> 6, d = n & 63;
        uint2 pk;
        pk.x = pkbf(acc[mi][ni][0] * scl, acc[mi][ni][1] * scl);
        pk.y = pkbf(acc[mi][ni][2] * scl, acc[mi][ni][3] * scl);
        *(uint2*)&out[(((size_t)(b * NHEADS + hh)) * HD + d) * S_LEN + s] = pk;
      }
  } else {
    unsigned short* out = (unsigned short*)outp + (size_t)z * QKV_STRIDE;
#pragma unroll
    for (int mi = 0; mi < 4; ++mi)
#pragma unroll
      for (int ni = 0; ni < 4; ++ni)
#pragma unroll
        for (int rg = 0; rg < 4; ++rg) {
          int m = m0 + wm * 64 + mi * 16 + fq * 4 + rg;
          int n = n0 + wn * 64 + ni * 16 + fr;
          int b = m >> 11, s = m & 2047, hh = n >> 6, d = n & 63;
          out[(((size_t)(b * NHEADS + hh)) * S_LEN + s) * HD + d] = f2bf(acc[mi][ni][rg]);
        }
  }
}

// ---------------- flash attention: split-k waves, fixed-base softmax ----------------
// 8 waves = 4 q-groups x 2 k-halves. Each wave: 32 q x 64 k -> K/V LDS reads per wave
// HALVE vs the 16q-per-wave form (224 KB vs 352 KB LDS traffic per block-iter) at the
// same MFMA count. Fixed-base softmax (no running max) makes the k-split linear:
// partial O and l are summed across wave pairs once at the end via LDS.
// Exchange record = 32 O floats + 2 l floats -> stride 34 (R7 bug: stride 18 overlapped
// records and collided O[e=4] with the l slots).
__global__ __launch_bounds__(512, 4) void attn_kernel(
    const unsigned short* __restrict__ Qtp,
    const unsigned short* __restrict__ Kp,
    const unsigned short* __restrict__ Vtp,
    const int* __restrict__ mask,
    unsigned short* __restrict__ ctx)
{
  __shared__ __align__(16) char smem[65536];
  unsigned short* sK  = (unsigned short*)smem;             // [128 k][64 d], 16B chunks xor k&7
  unsigned short* sVt = (unsigned short*)(smem + 16384);   // [64 d][128 k], 16B chunks xor d&15
  unsigned short* sP0 = (unsigned short*)(smem + 32768);   // 8 x [32 q][64 k] P^T strips

  const int bh = blockIdx.y;
  const int b = bh >> 4;
  const int h = bh & 15;
  const size_t base = (size_t)bh * (S_LEN * HD);
  const int q0 = blockIdx.x * 128;
  const int t = threadIdx.x;
  const int lane = t & 63;
  const int w = t >> 6;                        // 0..7
  const int qg = w >> 1;                       // q-group (32 q)
  const int kh = w & 1;                        // k-half (64 k)
  const int fr = lane & 15;
  const int fq = lane >> 4;
  unsigned short* sPw = sP0 + w * (32 * 64);

  // Q fragments (B-operand): 32 q rows, from transposed (b,h,d,s) layout
  short8 qfr[2][2];
#pragma unroll
  for (int q_ = 0; q_ < 2; ++q_)
#pragma unroll
    for (int ks = 0; ks < 2; ++ks)
#pragma unroll
      for (int j = 0; j < 8; ++j)
        qfr[q_][ks][j] = (short)Qtp[base + (size_t)(ks * 32 + fq * 8 + j) * S_LEN
                                    + (q0 + qg * 32 + q_ * 16 + fr)];

  float l_lane[2] = {0.f, 0.f};
  float4v o_acc[4][2] = {};                    // [df][q_], partial O^T over this k-half

  const int kr = lane >> 3, kc = lane & 7;     // K staging
  const int vr = lane >> 4, vc = lane & 15;    // Vt staging
  const float NEG = -1e30f;

  for (int kv0 = 0; kv0 < S_LEN; kv0 += 128) {
    __syncthreads();
    // stage K tile: wave w covers rows [w*16, w*16+16)
#pragma unroll
    for (int o = 0; o < 2; ++o) {
      int row0 = w * 16 + o * 8;
      async_copy16(Kp + base + (size_t)(kv0 + row0 + kr) * HD + ((kc ^ kr) * 8), &sK[row0 * HD]);
    }
    // stage V^T tile: wave w covers rows (d) [w*8, w*8+8)
#pragma unroll
    for (int o = 0; o < 2; ++o) {
      int d0 = w * 8 + o * 4;
      int d  = d0 + vr;
      async_copy16(Vtp + base + (size_t)d * S_LEN + kv0 + ((vc ^ (d & 15)) * 8), &sVt[d0 * 128]);
    }
    __syncthreads();

    // S^T = K · Q^T over this wave's k-half (kf 0..3)
    float4v s_acc[4][2];
    const float4v zero4 = {0.f, 0.f, 0.f, 0.f};
#pragma unroll
    for (int kf = 0; kf < 4; ++kf) {
      int rk = kh * 64 + kf * 16 + fr;
      short8 k0 = *(const short8*)&sK[rk * HD + ((fq ^ (fr & 7)) * 8)];
      short8 k1 = *(const short8*)&sK[rk * HD + (((4 + fq) ^ (fr & 7)) * 8)];
#pragma unroll
      for (int q_ = 0; q_ < 2; ++q_) {
        float4v s = __builtin_amdgcn_mfma_f32_16x16x32_bf16(k0, qfr[q_][0], zero4, 0, 0, 0);
        s_acc[kf][q_] = __builtin_amdgcn_mfma_f32_16x16x32_bf16(k1, qfr[q_][1], s, 0, 0, 0);
      }
    }

    // mask -> exp2 -> pack P^T strip -> per-lane l partials
    const int prow0 = fr * 64;
#pragma unroll
    for (int kf = 0; kf < 4; ++kf) {
      int4 mv = *(const int4*)&mask[b * S_LEN + kv0 + kh * 64 + kf * 16 + fq * 4];
#pragma unroll
      for (int q_ = 0; q_ < 2; ++q_) {
        float p0 = __builtin_amdgcn_exp2f(mv.x ? s_acc[kf][q_][0] : NEG);
        float p1 = __builtin_amdgcn_exp2f(mv.y ? s_acc[kf][q_][1] : NEG);
        float p2 = __builtin_amdgcn_exp2f(mv.z ? s_acc[kf][q_][2] : NEG);
        float p3 = __builtin_amdgcn_exp2f(mv.w ? s_acc[kf][q_][3] : NEG);
        l_lane[q_] += (p0 + p1) + (p2 + p3);
        uint2 pk;
        pk.x = pkbf(p0, p1);
        pk.y = pkbf(p2, p3);
        *(uint2*)&sPw[prow0 + q_ * 16 * 64 + (((kf * 4 + fq) ^ (fr & 14)) << 2)] = pk;
      }
    }
    // no barrier: sP strip is per-wave; LDS ops are in-order within a wave

    // O^T += V^T · P^T over this k-half (ks 0..1)
#pragma unroll
    for (int ks = 0; ks < 2; ++ks) {
      short8 pf[2], vf[4];
#pragma unroll
      for (int q_ = 0; q_ < 2; ++q_)
        pf[q_] = *(const short8*)&sPw[prow0 + q_ * 16 * 64 + (((ks * 8 + fq * 2) ^ (fr & 14)) << 2)];
#pragma unroll
      for (int df = 0; df < 4; ++df)
        vf[df] = *(const short8*)&sVt[(df * 16 + fr) * 128 + (((kh * 8 + ks * 4 + fq) ^ fr) << 3)];
#pragma unroll
      for (int df = 0; df < 4; ++df)
#pragma unroll
        for (int q_ = 0; q_ < 2; ++q_)
          o_acc[df][q_] = __builtin_amdgcn_mfma_f32_16x16x32_bf16(vf[df], pf[q_], o_acc[df][q_], 0, 0, 0);
    }
  }

  // reduce l over fq within the wave
#pragma unroll
  for (int q_ = 0; q_ < 2; ++q_) {
    l_lane[q_] += __shfl_xor(l_lane[q_], 16);
    l_lane[q_] += __shfl_xor(l_lane[q_], 32);
  }

  // cross-wave-pair (kh) reduction via LDS.
  // Record: 32 O floats + 2 l floats, stride 34 (136 B). 4 pairs x 64 lanes x 136 B
  // = 34816 B, aliasing sK+sVt+first 2KB of sP (all dead after the barrier).
  __syncthreads();   // all waves done with sK/sVt/sP before aliasing
  float* red = (float*)smem;
  float* rec = red + (size_t)(qg * 64 + lane) * 34;
  if (kh) {
#pragma unroll
    for (int df = 0; df < 4; ++df)
#pragma unroll
      for (int q_ = 0; q_ < 2; ++q_) {
        int e = df * 2 + q_;
        *(float2*)&rec[4 * e]     = make_float2(o_acc[df][q_][0], o_acc[df][q_][1]);
        *(float2*)&rec[4 * e + 2] = make_float2(o_acc[df][q_][2], o_acc[df][q_][3]);
      }
    *(float2*)&rec[32] = make_float2(l_lane[0], l_lane[1]);
  }
  __syncthreads();
  if (!kh) {
#pragma unroll
    for (int df = 0; df < 4; ++df)
#pragma unroll
      for (int q_ = 0; q_ < 2; ++q_) {
        int e = df * 2 + q_;
        float2 a = *(float2*)&rec[4 * e];
        float2 c = *(float2*)&rec[4 * e + 2];
        o_acc[df][q_][0] += a.x; o_acc[df][q_][1] += a.y;
        o_acc[df][q_][2] += c.x; o_acc[df][q_][3] += c.y;
      }
    float2 lr = *(float2*)&rec[32];
    float inv_l[2];
    inv_l[0] = 1.0f / (l_lane[0] + lr.x);
    inv_l[1] = 1.0f / (l_lane[1] + lr.y);
    // epilogue: O^T C-layout -> 4 consecutive d per lane -> packed 8B stores
#pragma unroll
    for (int q_ = 0; q_ < 2; ++q_) {
      size_t rowoff = ((size_t)(b * S_LEN + q0 + qg * 32 + q_ * 16 + fr)) * HDIM + h * HD;
#pragma unroll
      for (int df = 0; df < 4; ++df) {
        uint2 pk;
        pk.x = pkbf(o_acc[df][q_][0] * inv_l[q_], o_acc[df][q_][1] * inv_l[q_]);
        pk.y = pkbf(o_acc[df][q_][2] * inv_l[q_], o_acc[df][q_][3] * inv_l[q_]);
        *(uint2*)&ctx[rowoff + df * 16 + fq * 4] = pk;
      }
    }
  }
}

extern "C" void kernel_launch(void* const* d_in, const int* in_sizes, int n_in,
                              void* d_out, int out_size, void* d_ws, size_t ws_size,
                              hipStream_t stream) {
  const float* X  = (const float*)d_in[0];
  const int* mask = (const int*)d_in[1];
  const float* Wq = (const float*)d_in[2];
  const float* Wk = (const float*)d_in[3];
  const float* Wv = (const float*)d_in[4];
  const float* Wo = (const float*)d_in[5];
  float* out = (float*)d_out;

  char* ws = (char*)d_ws;
  // layout (40 MB): [0,8M) Xb then reused as CTX; [8M,16M) Wt x4; [16M,40M) Q^T,K,V^T bf16
  unsigned short* Xb  = (unsigned short*)(ws);
  unsigned short* Wt  = (unsigned short*)(ws + (8u << 20));
  unsigned short* QKV = (unsigned short*)(ws + (16u << 20));
  unsigned short* CTX = (unsigned short*)(ws);   // reuse Xb region (dead after QKV GEMM)

  cast_x_kernel<<<4096, 256, 0, stream>>>(X, Xb);
  trans_w_kernel<<<dim3(16, 16, 4), 256, 0, stream>>>(Wq, Wk, Wv, Wo, Wt);
  gemm128_kernel<<<dim3(32, 8, 3), 256, 0, stream>>>(
      Xb, Wt, Wt + (1u << 20), Wt + (2u << 20), QKV, 1);
  attn_kernel<<<dim3(16, 32), 512, 0, stream>>>(
      QKV, QKV + QKV_STRIDE, QKV + 2 * (size_t)QKV_STRIDE, mask, CTX);
  gemm128_kernel<<<dim3(32, 8, 1), 256, 0, stream>>>(
      CTX, Wt + (3u << 20), Wt + (3u << 20), Wt + (3u << 20), out, 0);
}

// Round 10
// 192.069 us; speedup vs baseline: 1.4579x; 1.0292x over previous
//
#include <hip/hip_runtime.h>
#include <hip/hip_bf16.h>

#define S_LEN 2048
#define HDIM  1024
#define NHEADS 16
#define HD    64
#define QKV_STRIDE (S_LEN * 2 * HDIM)   // 4194304 elements per tensor

typedef __attribute__((ext_vector_type(8))) short short8;
typedef __attribute__((ext_vector_type(4))) float float4v;

// cheap bf16 convert: round-half-up (bias ~2^-24 rel, negligible vs bf16 eps)
__device__ __forceinline__ unsigned short f2bf(float f) {
  return (unsigned short)((__builtin_bit_cast(unsigned int, f) + 0x8000u) >> 16);
}
// pack two floats -> two bf16 in one u32 via v_perm_b32 (3 VALU ops)
__device__ __forceinline__ unsigned int pkbf(float a, float b) {
  unsigned int ua = __builtin_bit_cast(unsigned int, a) + 0x8000u;
  unsigned int ub = __builtin_bit_cast(unsigned int, b) + 0x8000u;
  return __builtin_amdgcn_perm(ub, ua, 0x07060302u);  // {ub.hi16, ua.hi16}
}

__device__ __forceinline__ void async_copy16(const void* g, void* l) {
  __builtin_amdgcn_global_load_lds((__attribute__((address_space(1))) const void*)g,
                                   (__attribute__((address_space(3))) void*)l, 16, 0, 0);
}

// ---------------- cast X (fp32 -> bf16), 4 elems/thread ----------------
__global__ void cast_x_kernel(const float* __restrict__ X, unsigned short* __restrict__ Xb) {
  int i = blockIdx.x * blockDim.x + threadIdx.x;   // 0 .. 1048575
  float4 v = ((const float4*)X)[i];
  uint2 o;
  o.x = pkbf(v.x, v.y);
  o.y = pkbf(v.z, v.w);
  ((uint2*)Xb)[i] = o;
}

// ------------- transpose + cast weights: Wt[n][k] = bf16(W[k][n]) -------------
__global__ void trans_w_kernel(const float* __restrict__ W0, const float* __restrict__ W1,
                               const float* __restrict__ W2, const float* __restrict__ W3,
                               unsigned short* __restrict__ Wt) {
  __shared__ unsigned short tile[64][72];   // [n_loc][k_loc], padded
  const float* W = (blockIdx.z == 0) ? W0 : (blockIdx.z == 1) ? W1 : (blockIdx.z == 2) ? W2 : W3;
  unsigned short* out = Wt + (size_t)blockIdx.z * HDIM * HDIM;
  int n0 = blockIdx.x * 64, k0 = blockIdx.y * 64;
  int t = threadIdx.x;
#pragma unroll
  for (int it = 0; it < 4; ++it) {
    int idx = it * 256 + t;          // 1024 float4 chunks
    int r  = idx >> 4;               // k_loc 0..63
    int c4 = (idx & 15) * 4;         // n_loc
    float4 v = *(const float4*)&W[(size_t)(k0 + r) * HDIM + n0 + c4];
    tile[c4 + 0][r] = f2bf(v.x);
    tile[c4 + 1][r] = f2bf(v.y);
    tile[c4 + 2][r] = f2bf(v.z);
    tile[c4 + 3][r] = f2bf(v.w);
  }
  __syncthreads();
#pragma unroll
  for (int it = 0; it < 4; ++it) {
    int idx = it * 256 + t;
    int r  = idx >> 4;               // n_loc
    int c4 = (idx & 15) * 4;         // k_loc
    ushort4 o;
    o.x = tile[r][c4 + 0]; o.y = tile[r][c4 + 1];
    o.z = tile[r][c4 + 2]; o.w = tile[r][c4 + 3];
    *(ushort4*)&out[(size_t)(n0 + r) * HDIM + k0 + c4] = o;
  }
}

// ---------------- 128x128 bf16 MFMA GEMM, A(MxK) row-major, Bt(NxK) row-major ----------------
// mode 0: fp32 dense out[m*1024+n].
// mode 1: bf16; z==1 (K) -> (b,h,s,d) natural scatter;
//               z==0 (Q, pre-scaled by 0.125*log2e) and z==2 (V) -> (b,h,d,s) packed.
__global__ __launch_bounds__(256, 3) void gemm128_kernel(
    const unsigned short* __restrict__ A,
    const unsigned short* __restrict__ B0, const unsigned short* __restrict__ B1,
    const unsigned short* __restrict__ B2,
    void* __restrict__ outp, int mode)
{
  __shared__ unsigned short sA[128 * 32];
  __shared__ unsigned short sB[128 * 32];
  const int z = blockIdx.z;
  const unsigned short* Bt = (z == 0) ? B0 : (z == 1) ? B1 : B2;
  const int m0 = blockIdx.x * 128;
  const int n0 = blockIdx.y * 128;
  const int t = threadIdx.x;
  const int lane = t & 63;
  const int w = t >> 6;
  const int wm = w & 1, wn = w >> 1;

  const int sr  = lane >> 2;                  // row within 16
  const int scp = lane & 3;                   // physical chunk
  const int scl = scp ^ ((sr >> 1) & 3);      // logical (global) k-chunk
  const long ga0 = (long)(m0 + 16 * w + sr) * HDIM + scl * 8;
  const long ga1 = ga0 + 64l * HDIM;
  const long gb0 = (long)(n0 + 16 * w + sr) * HDIM + scl * 8;
  const long gb1 = gb0 + 64l * HDIM;
  unsigned short* lA0 = &sA[(16 * w) * 32];
  unsigned short* lA1 = &sA[(64 + 16 * w) * 32];
  unsigned short* lB0 = &sB[(16 * w) * 32];
  unsigned short* lB1 = &sB[(64 + 16 * w) * 32];

  const int fr = lane & 15;
  const int fq = lane >> 4;
  int offA[4], offB[4];
#pragma unroll
  for (int i = 0; i < 4; ++i) {
    int ra = wm * 64 + i * 16 + fr;
    offA[i] = ra * 32 + (fq ^ ((ra >> 1) & 3)) * 8;
    int rb = wn * 64 + i * 16 + fr;
    offB[i] = rb * 32 + (fq ^ ((rb >> 1) & 3)) * 8;
  }

  float4v acc[4][4] = {};

  for (int kk = 0; kk < HDIM; kk += 32) {
    __syncthreads();
    async_copy16(A + ga0 + kk, lA0);
    async_copy16(A + ga1 + kk, lA1);
    async_copy16(Bt + gb0 + kk, lB0);
    async_copy16(Bt + gb1 + kk, lB1);
    __syncthreads();
    short8 af[4], bf[4];
#pragma unroll
    for (int i = 0; i < 4; ++i) af[i] = *(const short8*)&sA[offA[i]];
#pragma unroll
    for (int i = 0; i < 4; ++i) bf[i] = *(const short8*)&sB[offB[i]];
#pragma unroll
    for (int mi = 0; mi < 4; ++mi)
#pragma unroll
      for (int ni = 0; ni < 4; ++ni)
        acc[mi][ni] = __builtin_amdgcn_mfma_f32_16x16x32_bf16(af[mi], bf[ni], acc[mi][ni], 0, 0, 0);
  }

  if (mode == 0) {
    float* out = (float*)outp;
#pragma unroll
    for (int mi = 0; mi < 4; ++mi)
#pragma unroll
      for (int ni = 0; ni < 4; ++ni)
#pragma unroll
        for (int rg = 0; rg < 4; ++rg) {
          int m = m0 + wm * 64 + mi * 16 + fq * 4 + rg;
          int n = n0 + wn * 64 + ni * 16 + fr;
          out[(size_t)m * HDIM + n] = acc[mi][ni][rg];
        }
  } else if (z != 1) {
    // transposed (b, h, d, s): 4 consecutive s per lane -> packed 8B stores.
    // z==0 (Q): fold softmax scale 0.125*log2(e) in here.
    const float scl = (z == 0) ? 0.18033688011112042f : 1.0f;
    unsigned short* out = (unsigned short*)outp + (size_t)z * QKV_STRIDE;
#pragma unroll
    for (int mi = 0; mi < 4; ++mi)
#pragma unroll
      for (int ni = 0; ni < 4; ++ni) {
        int m = m0 + wm * 64 + mi * 16 + fq * 4;   // s base (multiple of 4)
        int n = n0 + wn * 64 + ni * 16 + fr;
        int b = m >> 11, s = m & 2047, hh = n >> 6, d = n & 63;
        uint2 pk;
        pk.x = pkbf(acc[mi][ni][0] * scl, acc[mi][ni][1] * scl);
        pk.y = pkbf(acc[mi][ni][2] * scl, acc[mi][ni][3] * scl);
        *(uint2*)&out[(((size_t)(b * NHEADS + hh)) * HD + d) * S_LEN + s] = pk;
      }
  } else {
    unsigned short* out = (unsigned short*)outp + (size_t)z * QKV_STRIDE;
#pragma unroll
    for (int mi = 0; mi < 4; ++mi)
#pragma unroll
      for (int ni = 0; ni < 4; ++ni)
#pragma unroll
        for (int rg = 0; rg < 4; ++rg) {
          int m = m0 + wm * 64 + mi * 16 + fq * 4 + rg;
          int n = n0 + wn * 64 + ni * 16 + fr;
          int b = m >> 11, s = m & 2047, hh = n >> 6, d = n & 63;
          out[(((size_t)(b * NHEADS + hh)) * S_LEN + s) * HD + d] = f2bf(acc[mi][ni][rg]);
        }
  }
}

// stage one 64-k tile (K 8 KB + V^T 8 KB) into buffer (tile&1); 2 DMA copies per wave
__device__ __forceinline__ void stage_tile(char* smem, const unsigned short* Kp,
    const unsigned short* Vtp, size_t base, int tile, int w, int kr, int kc) {
  const int kv = tile * 64;
  char* bufb = smem + (tile & 1) * 16384;
  unsigned short* dK = (unsigned short*)bufb + (w * 8) * 64;
  async_copy16(Kp + base + (size_t)(kv + w * 8 + kr) * HD + ((kc ^ kr) * 8), dK);
  unsigned short* dV = (unsigned short*)(bufb + 8192) + (w * 8) * 64;
  const int d = w * 8 + kr;
  async_copy16(Vtp + base + (size_t)d * S_LEN + kv + ((kc ^ kr) * 8), dV);
}

// ---------------- flash attention: split-k waves, fixed-base softmax, ----------------
// ---------------- BN=64 double-buffered staging, ONE barrier per tile ----------------
// Pipeline: stage(0); loop{ barrier; stage(it+1 -> other buf); compute(buf it&1); }.
// The compiler's vmcnt(0)-before-s_barrier now drains copies issued a full compute
// phase earlier -> staging latency hidden, half the barriers of the 2-barrier form.
// 8 waves = 4 q-groups x 2 k-halves (32 q x 32 k each). Fixed-base softmax keeps the
// k-split linear; O/l partials merged across wave pairs once at the end via LDS.
// LDS 52 KB: [0,32K) K/V dbuf, [32K,52K) per-wave P strips (32 rows x 80 B, padded ->
// b128 reads bank-perfect). R9 bug fixed here: V-buffer read offset was computed in
// ELEMENTS (sKb+8192) instead of BYTES -> PV read the wrong buffer. Now byte-based.
__global__ __launch_bounds__(512, 4) void attn_kernel(
    const unsigned short* __restrict__ Qtp,
    const unsigned short* __restrict__ Kp,
    const unsigned short* __restrict__ Vtp,
    const int* __restrict__ mask,
    unsigned short* __restrict__ ctx)
{
  __shared__ __align__(16) char smem[53248];

  const int bh = blockIdx.y;
  const int b = bh >> 4;
  const int h = bh & 15;
  const size_t base = (size_t)bh * (S_LEN * HD);
  const int q0 = blockIdx.x * 128;
  const int t = threadIdx.x;
  const int lane = t & 63;
  const int w = t >> 6;                        // 0..7
  const int qg = w >> 1;                       // q-group (32 q)
  const int kh = w & 1;                        // k-half (32 k)
  const int fr = lane & 15;
  const int fq = lane >> 4;
  const int kr = lane >> 3, kc = lane & 7;     // staging lane map
  unsigned short* sPw = (unsigned short*)(smem + 32768) + w * (32 * 40);

  // Q fragments (B-operand): 32 q rows, from transposed (b,h,d,s) layout
  short8 qfr[2][2];
#pragma unroll
  for (int q_ = 0; q_ < 2; ++q_)
#pragma unroll
    for (int ks = 0; ks < 2; ++ks)
#pragma unroll
      for (int j = 0; j < 8; ++j)
        qfr[q_][ks][j] = (short)Qtp[base + (size_t)(ks * 32 + fq * 8 + j) * S_LEN
                                    + (q0 + qg * 32 + q_ * 16 + fr)];

  float l_lane[2] = {0.f, 0.f};
  float4v o_acc[4][2] = {};                    // [df][q_], partial O^T over this k-half
  const float NEG = -1e30f;
  const float4v zero4 = {0.f, 0.f, 0.f, 0.f};

  // prologue: stage tile 0 into buffer 0
  stage_tile(smem, Kp, Vtp, base, 0, w, kr, kc);

#pragma unroll 2
  for (int it = 0; it < 32; ++it) {
    __syncthreads();   // drains vmcnt -> tile 'it' resident; buffer (it+1)&1 free
    if (it < 31)
      stage_tile(smem, Kp, Vtp, base, it + 1, w, kr, kc);   // in flight during compute

    const unsigned short* sKb  = (const unsigned short*)(smem + (it & 1) * 16384);
    const unsigned short* sVtb = (const unsigned short*)(smem + (it & 1) * 16384 + 8192);
    const int kv0 = it * 64;

    // S^T = K · Q^T over this wave's 32-k strip (scores in log2 domain: Q pre-scaled)
    float4v s_acc[2][2];
#pragma unroll
    for (int kf = 0; kf < 2; ++kf) {
      int rk = kh * 32 + kf * 16 + fr;
      short8 k0 = *(const short8*)&sKb[rk * 64 + ((fq ^ (rk & 7)) * 8)];
      short8 k1 = *(const short8*)&sKb[rk * 64 + (((4 + fq) ^ (rk & 7)) * 8)];
#pragma unroll
      for (int q_ = 0; q_ < 2; ++q_) {
        float4v s = __builtin_amdgcn_mfma_f32_16x16x32_bf16(k0, qfr[q_][0], zero4, 0, 0, 0);
        s_acc[kf][q_] = __builtin_amdgcn_mfma_f32_16x16x32_bf16(k1, qfr[q_][1], s, 0, 0, 0);
      }
    }

    // mask -> exp2 -> pack P^T strip -> per-lane l partials (no cross-lane ops)
#pragma unroll
    for (int kf = 0; kf < 2; ++kf) {
      int4 mv = *(const int4*)&mask[b * S_LEN + kv0 + kh * 32 + kf * 16 + fq * 4];
#pragma unroll
      for (int q_ = 0; q_ < 2; ++q_) {
        float p0 = __builtin_amdgcn_exp2f(mv.x ? s_acc[kf][q_][0] : NEG);
        float p1 = __builtin_amdgcn_exp2f(mv.y ? s_acc[kf][q_][1] : NEG);
        float p2 = __builtin_amdgcn_exp2f(mv.z ? s_acc[kf][q_][2] : NEG);
        float p3 = __builtin_amdgcn_exp2f(mv.w ? s_acc[kf][q_][3] : NEG);
        l_lane[q_] += (p0 + p1) + (p2 + p3);
        uint2 pk;
        pk.x = pkbf(p0, p1);
        pk.y = pkbf(p2, p3);
        *(uint2*)&sPw[(q_ * 16 + fr) * 40 + (kf * 4 + fq) * 4] = pk;
      }
    }
    // no barrier: sP strip is per-wave; LDS ops are in-order within a wave

    // O^T += V^T · P^T over this wave's 32-k strip (single k-step)
    short8 pf[2], vf[4];
#pragma unroll
    for (int q_ = 0; q_ < 2; ++q_)
      pf[q_] = *(const short8*)&sPw[(q_ * 16 + fr) * 40 + fq * 8];
#pragma unroll
    for (int df = 0; df < 4; ++df) {
      int rv = df * 16 + fr;
      vf[df] = *(const short8*)&sVtb[rv * 64 + (((kh * 4 + fq) ^ (fr & 7)) * 8)];
    }
#pragma unroll
    for (int df = 0; df < 4; ++df)
#pragma unroll
      for (int q_ = 0; q_ < 2; ++q_)
        o_acc[df][q_] = __builtin_amdgcn_mfma_f32_16x16x32_bf16(vf[df], pf[q_], o_acc[df][q_], 0, 0, 0);
  }

  // reduce l over fq within the wave
#pragma unroll
  for (int q_ = 0; q_ < 2; ++q_) {
    l_lane[q_] += __shfl_xor(l_lane[q_], 16);
    l_lane[q_] += __shfl_xor(l_lane[q_], 32);
  }

  // cross-wave-pair (kh) reduction via LDS.
  // Record: 32 O floats + 2 l floats, stride 34 (136 B). 4 pairs x 64 lanes x 136 B
  // = 34816 B, aliasing the dbuf + wave-0's P strip (all dead after the barrier).
  __syncthreads();   // all waves done with buffers/strips before aliasing
  float* red = (float*)smem;
  float* rec = red + (size_t)(qg * 64 + lane) * 34;
  if (kh) {
#pragma unroll
    for (int df = 0; df < 4; ++df)
#pragma unroll
      for (int q_ = 0; q_ < 2; ++q_) {
        int e = df * 2 + q_;
        *(float2*)&rec[4 * e]     = make_float2(o_acc[df][q_][0], o_acc[df][q_][1]);
        *(float2*)&rec[4 * e + 2] = make_float2(o_acc[df][q_][2], o_acc[df][q_][3]);
      }
    *(float2*)&rec[32] = make_float2(l_lane[0], l_lane[1]);
  }
  __syncthreads();
  if (!kh) {
#pragma unroll
    for (int df = 0; df < 4; ++df)
#pragma unroll
      for (int q_ = 0; q_ < 2; ++q_) {
        int e = df * 2 + q_;
        float2 a = *(float2*)&rec[4 * e];
        float2 c = *(float2*)&rec[4 * e + 2];
        o_acc[df][q_][0] += a.x; o_acc[df][q_][1] += a.y;
        o_acc[df][q_][2] += c.x; o_acc[df][q_][3] += c.y;
      }
    float2 lr = *(float2*)&rec[32];
    float inv_l[2];
    inv_l[0] = 1.0f / (l_lane[0] + lr.x);
    inv_l[1] = 1.0f / (l_lane[1] + lr.y);
    // epilogue: O^T C-layout -> 4 consecutive d per lane -> packed 8B stores
#pragma unroll
    for (int q_ = 0; q_ < 2; ++q_) {
      size_t rowoff = ((size_t)(b * S_LEN + q0 + qg * 32 + q_ * 16 + fr)) * HDIM + h * HD;
#pragma unroll
      for (int df = 0; df < 4; ++df) {
        uint2 pk;
        pk.x = pkbf(o_acc[df][q_][0] * inv_l[q_], o_acc[df][q_][1] * inv_l[q_]);
        pk.y = pkbf(o_acc[df][q_][2] * inv_l[q_], o_acc[df][q_][3] * inv_l[q_]);
        *(uint2*)&ctx[rowoff + df * 16 + fq * 4] = pk;
      }
    }
  }
}

extern "C" void kernel_launch(void* const* d_in, const int* in_sizes, int n_in,
                              void* d_out, int out_size, void* d_ws, size_t ws_size,
                              hipStream_t stream) {
  const float* X  = (const float*)d_in[0];
  const int* mask = (const int*)d_in[1];
  const float* Wq = (const float*)d_in[2];
  const float* Wk = (const float*)d_in[3];
  const float* Wv = (const float*)d_in[4];
  const float* Wo = (const float*)d_in[5];
  float* out = (float*)d_out;

  char* ws = (char*)d_ws;
  // layout (40 MB): [0,8M) Xb then reused as CTX; [8M,16M) Wt x4; [16M,40M) Q^T,K,V^T bf16
  unsigned short* Xb  = (unsigned short*)(ws);
  unsigned short* Wt  = (unsigned short*)(ws + (8u << 20));
  unsigned short* QKV = (unsigned short*)(ws + (16u << 20));
  unsigned short* CTX = (unsigned short*)(ws);   // reuse Xb region (dead after QKV GEMM)

  cast_x_kernel<<<4096, 256, 0, stream>>>(X, Xb);
  trans_w_kernel<<<dim3(16, 16, 4), 256, 0, stream>>>(Wq, Wk, Wv, Wo, Wt);
  gemm128_kernel<<<dim3(32, 8, 3), 256, 0, stream>>>(
      Xb, Wt, Wt + (1u << 20), Wt + (2u << 20), QKV, 1);
  attn_kernel<<<dim3(16, 32), 512, 0, stream>>>(
      QKV, QKV + QKV_STRIDE, QKV + 2 * (size_t)QKV_STRIDE, mask, CTX);
  gemm128_kernel<<<dim3(32, 8, 1), 256, 0, stream>>>(
      CTX, Wt + (3u << 20), Wt + (3u << 20), Wt + (3u << 20), out, 0);
}